// Round 5
// baseline (252.912 us; speedup 1.0000x reference)
//
#include <hip/hip_runtime.h>
#include <cstdint>

// Problem constants: B=4, S=1024, D=768, H=12, dh=64
#define BB 4
#define SS 1024
#define DD 768
#define HH 12
#define DH 64

typedef unsigned short u16;
typedef unsigned int   u32;
typedef __attribute__((ext_vector_type(8))) short bf16x8;
typedef __attribute__((ext_vector_type(4))) float f32x4;

// fp32 -> bf16 RNE (finite values)
__device__ __forceinline__ u16 f2bf(float f) {
    u32 u = __float_as_uint(f);
    u += 0x7fffu + ((u >> 16) & 1u);
    return (u16)(u >> 16);
}
__device__ __forceinline__ float b2f(u32 lo16) {
    return __uint_as_float(lo16 << 16);
}

// 2^x via v_exp_f32 (gfx950 exp is base-2)
__device__ __forceinline__ float fast_exp2(float x) {
    return __builtin_amdgcn_exp2f(x);
}

// pack two f32 -> packed bf16x2. gfx950 has V_CVT_PK_BF16_F32.
#if __has_builtin(__builtin_amdgcn_cvt_pk_bf16_f32)
__device__ __forceinline__ u32 pack2(float a, float b) {
    auto r = __builtin_amdgcn_cvt_pk_bf16_f32(a, b);
    u32 v; __builtin_memcpy(&v, &r, 4); return v;
}
#else
__device__ __forceinline__ u32 pack2(float a, float b) {
    return (u32)f2bf(a) | ((u32)f2bf(b) << 16);
}
#endif

// async global->LDS, 16 B per lane. GLOBAL pointer is PER-LANE; LDS dest is
// wave-uniform base, HW adds lane*16 (m104/m108).
#define ASYNC16(gp, lp) __builtin_amdgcn_global_load_lds( \
    (const __attribute__((address_space(1))) void*)(gp),  \
    (__attribute__((address_space(3))) void*)(lp), 16, 0, 0)

// ---------------- MFMA GEMM body (NT: A[M,K], B[N,K], both K-contiguous bf16) ----
template<int BM_, int BN_, class Epi>
__device__ __forceinline__ void mfma_gemm(
    const u16* __restrict__ A, const u16* __restrict__ B,
    int K, int lda, int ldb, int m0, int n0, const Epi& epi)
{
    constexpr int MI = BM_ / 32;
    constexpr int NJ = BN_ / 32;
    __shared__ u16 Alds[BM_ * 32];
    __shared__ u16 Blds[BN_ * 32];

    const int tid  = threadIdx.x;
    const int wave = tid >> 6;
    const int lane = tid & 63;
    const int wr = wave >> 1, wc = wave & 1;

    const int ar = lane >> 2;
    const int ac = (lane & 3) * 8;

    f32x4 acc[MI][NJ] = {};

    for (int k0 = 0; k0 < K; k0 += 32) {
        __syncthreads();
#pragma unroll
        for (int j = 0; j < BM_ / 64; ++j) {
            const int rb = wave * (BM_ / 4) + j * 16;
            ASYNC16(A + (size_t)(m0 + rb + ar) * lda + k0 + ac, &Alds[rb * 32]);
        }
#pragma unroll
        for (int j = 0; j < BN_ / 64; ++j) {
            const int rb = wave * (BN_ / 4) + j * 16;
            ASYNC16(B + (size_t)(n0 + rb + ar) * ldb + k0 + ac, &Blds[rb * 32]);
        }
        __syncthreads();

        bf16x8 af[MI], bfr[NJ];
#pragma unroll
        for (int mi = 0; mi < MI; ++mi)
            af[mi] = *(const bf16x8*)&Alds[(wr * (BM_ / 2) + mi * 16 + (lane & 15)) * 32 + (lane >> 4) * 8];
#pragma unroll
        for (int nj = 0; nj < NJ; ++nj)
            bfr[nj] = *(const bf16x8*)&Blds[(wc * (BN_ / 2) + nj * 16 + (lane & 15)) * 32 + (lane >> 4) * 8];
#pragma unroll
        for (int mi = 0; mi < MI; ++mi)
#pragma unroll
            for (int nj = 0; nj < NJ; ++nj)
                acc[mi][nj] = __builtin_amdgcn_mfma_f32_16x16x32_bf16(
                    af[mi], bfr[nj], acc[mi][nj], 0, 0, 0);
    }

#pragma unroll
    for (int mi = 0; mi < MI; ++mi)
#pragma unroll
        for (int nj = 0; nj < NJ; ++nj)
#pragma unroll
            for (int r = 0; r < 4; ++r)
                epi(m0 + wr * (BM_ / 2) + mi * 16 + (lane >> 4) * 4 + r,
                    n0 + wc * (BN_ / 2) + nj * 16 + (lane & 15),
                    acc[mi][nj][r]);
}

// padded Clds row length (u16)
#define CPAD 136

// ---------------- qkv GEMM (custom, LDS-coalesced epilogue) ----------------
__global__ __launch_bounds__(256) void qkv_gemm_kernel(
    const u16* __restrict__ xb, const u16* __restrict__ Wt,
    const float* __restrict__ bias,
    u16* __restrict__ qb, u16* __restrict__ kb, u16* __restrict__ vb)
{
    __shared__ u16 Alds[128 * 32];
    __shared__ u16 Blds[128 * 32];
    __shared__ u16 Clds[128 * CPAD];

    const int tid  = threadIdx.x;
    const int wave = tid >> 6;
    const int lane = tid & 63;
    const int wr = wave >> 1, wc = wave & 1;
    const int ar = lane >> 2;
    const int ac = (lane & 3) * 8;
    const int m0 = blockIdx.y * 128, n0 = blockIdx.x * 128;

    f32x4 acc[4][4] = {};

    for (int k0 = 0; k0 < DD; k0 += 32) {
        __syncthreads();
#pragma unroll
        for (int j = 0; j < 2; ++j) {
            const int rb = wave * 32 + j * 16;
            ASYNC16(xb + (size_t)(m0 + rb + ar) * DD + k0 + ac, &Alds[rb * 32]);
            ASYNC16(Wt + (size_t)(n0 + rb + ar) * DD + k0 + ac, &Blds[rb * 32]);
        }
        __syncthreads();

        bf16x8 af[4], bfr[4];
#pragma unroll
        for (int mi = 0; mi < 4; ++mi)
            af[mi] = *(const bf16x8*)&Alds[(wr * 64 + mi * 16 + (lane & 15)) * 32 + (lane >> 4) * 8];
#pragma unroll
        for (int nj = 0; nj < 4; ++nj)
            bfr[nj] = *(const bf16x8*)&Blds[(wc * 64 + nj * 16 + (lane & 15)) * 32 + (lane >> 4) * 8];
#pragma unroll
        for (int mi = 0; mi < 4; ++mi)
#pragma unroll
            for (int nj = 0; nj < 4; ++nj)
                acc[mi][nj] = __builtin_amdgcn_mfma_f32_16x16x32_bf16(
                    af[mi], bfr[nj], acc[mi][nj], 0, 0, 0);
    }

    const int c  = n0 / DD;
    const int w0 = n0 - c * DD;
    const int hA = w0 >> 6;
    const float qs = (c == 0) ? 0.125f : 1.0f;
#pragma unroll
    for (int mi = 0; mi < 4; ++mi)
#pragma unroll
        for (int nj = 0; nj < 4; ++nj)
#pragma unroll
            for (int r = 0; r < 4; ++r) {
                const int row = wr * 64 + mi * 16 + (lane >> 4) * 4 + r;
                const int col = wc * 64 + nj * 16 + (lane & 15);
                Clds[row * CPAD + col] = f2bf((acc[mi][nj][r] + bias[n0 + col]) * qs);
            }
    __syncthreads();

    u16* const dst = (c == 0) ? qb : (c == 1) ? kb : vb;
    const int b = m0 >> 10;
#pragma unroll
    for (int j = 0; j < 8; ++j) {
        const int idx = j * 256 + tid;
        const int row = idx >> 4, u4 = idx & 15;
        const int half = u4 >> 3, d8 = u4 & 7;
        const int h = hA + half;
        const int s = (m0 + row) & 1023;
        const uint4 v = *(const uint4*)&Clds[row * CPAD + half * 64 + d8 * 8];
        *(uint4*)&dst[(((size_t)(b * HH + h) << 10) + s) * DH + d8 * 8] = v;
    }
}

// ---------------- vb -> vt transpose (per bh: 1024x64 -> 64x1024) ----------
__global__ __launch_bounds__(256) void vtrans_kernel(
    const u16* __restrict__ vb, u16* __restrict__ vt)
{
    __shared__ u16 t[64 * 72];
    const int tid = threadIdx.x;
    const int bh = blockIdx.y;
    const int s0 = blockIdx.x * 64;
    const u16* src = vb + ((size_t)bh << 16) + (size_t)s0 * DH;

#pragma unroll
    for (int j = 0; j < 2; ++j) {
        const int idx = j * 256 + tid;
        const int row = idx >> 3, u4 = idx & 7;
        *(uint4*)&t[row * 72 + u4 * 8] = *(const uint4*)&src[row * DH + u4 * 8];
    }
    __syncthreads();

#pragma unroll
    for (int j = 0; j < 2; ++j) {
        const int idx = j * 256 + tid;
        const int d = idx >> 3, u4 = idx & 7;
        u16 tmp[8];
#pragma unroll
        for (int i = 0; i < 8; ++i) tmp[i] = t[(u4 * 8 + i) * 72 + d];
        *(uint4*)&vt[((size_t)bh * DH + d) * SS + s0 + u4 * 8] = *(const uint4*)tmp;
    }
}

// ---------------- qk GEMM (custom, LDS-coalesced epilogue) -----------------
__global__ __launch_bounds__(256) void qk_gemm_kernel(
    const u16* __restrict__ qb, const u16* __restrict__ kb,
    u16* __restrict__ attn, int bh0)
{
    __shared__ u16 Alds[128 * 32];
    __shared__ u16 Blds[128 * 32];
    __shared__ u16 Clds[128 * CPAD];

    const int tid  = threadIdx.x;
    const int wave = tid >> 6;
    const int lane = tid & 63;
    const int wr = wave >> 1, wc = wave & 1;
    const int ar = lane >> 2;
    const int ac = (lane & 3) * 8;
    const int m0 = blockIdx.y * 128, n0 = blockIdx.x * 128;

    const int bhL = blockIdx.z;
    const u16* A = qb + (size_t)(bh0 + bhL) * SS * DH;
    const u16* B = kb + (size_t)(bh0 + bhL) * SS * DH;
    u16* C = attn + (size_t)bhL * SS * SS;

    f32x4 acc[4][4] = {};

#pragma unroll
    for (int k0 = 0; k0 < DH; k0 += 32) {
        __syncthreads();
#pragma unroll
        for (int j = 0; j < 2; ++j) {
            const int rb = wave * 32 + j * 16;
            ASYNC16(A + (size_t)(m0 + rb + ar) * DH + k0 + ac, &Alds[rb * 32]);
            ASYNC16(B + (size_t)(n0 + rb + ar) * DH + k0 + ac, &Blds[rb * 32]);
        }
        __syncthreads();

        bf16x8 af[4], bfr[4];
#pragma unroll
        for (int mi = 0; mi < 4; ++mi)
            af[mi] = *(const bf16x8*)&Alds[(wr * 64 + mi * 16 + (lane & 15)) * 32 + (lane >> 4) * 8];
#pragma unroll
        for (int nj = 0; nj < 4; ++nj)
            bfr[nj] = *(const bf16x8*)&Blds[(wc * 64 + nj * 16 + (lane & 15)) * 32 + (lane >> 4) * 8];
#pragma unroll
        for (int mi = 0; mi < 4; ++mi)
#pragma unroll
            for (int nj = 0; nj < 4; ++nj)
                acc[mi][nj] = __builtin_amdgcn_mfma_f32_16x16x32_bf16(
                    af[mi], bfr[nj], acc[mi][nj], 0, 0, 0);
    }

#pragma unroll
    for (int mi = 0; mi < 4; ++mi)
#pragma unroll
        for (int nj = 0; nj < 4; ++nj)
#pragma unroll
            for (int r = 0; r < 4; ++r) {
                const int row = wr * 64 + mi * 16 + (lane >> 4) * 4 + r;
                const int col = wc * 64 + nj * 16 + (lane & 15);
                Clds[row * CPAD + col] = f2bf(acc[mi][nj][r]);
            }
    __syncthreads();

#pragma unroll
    for (int j = 0; j < 8; ++j) {
        const int idx = j * 256 + tid;
        const int row = idx >> 4, u4 = idx & 15;
        *(uint4*)&C[(size_t)(m0 + row) * SS + n0 + u4 * 8] =
            *(const uint4*)&Clds[row * CPAD + u4 * 8];
    }
}

// ---------------- pv (64x64 tile) ------------------------------------------
__global__ __launch_bounds__(256) void pv_gemm_kernel(
    const u16* __restrict__ attn2, const u16* __restrict__ vt,
    u16* __restrict__ ctx, int bh0)
{
    const int bhL = blockIdx.z;
    const int bh = bh0 + bhL;
    const int b = bh / HH, h = bh % HH;
    const u16* A = attn2 + (size_t)bhL * SS * SS;
    const u16* B = vt + (size_t)bh * DH * SS;
    u16* C = ctx + (size_t)b * SS * DD + h * DH;
    struct Epi {
        u16* C;
        __device__ void operator()(int m, int n, float v) const {
            C[(size_t)m * DD + n] = f2bf(v);
        }
    } epi{C};
    mfma_gemm<64, 64>(A, B, SS, SS, SS, blockIdx.y * 64, 0, epi);
}

// ---------------- proj (template) ------------------------------------------
__global__ __launch_bounds__(256) void proj_gemm_kernel(
    const u16* __restrict__ ctx, const u16* __restrict__ Wt,
    const float* __restrict__ bias, float* __restrict__ out)
{
    struct Epi {
        float* out; const float* bias;
        __device__ void operator()(int m, int n, float v) const {
            out[(size_t)m * DD + n] = v + bias[n];
        }
    } epi{out, bias};
    mfma_gemm<128, 64>(ctx, Wt, DD, DD, DD, blockIdx.y * 128, blockIdx.x * 64, epi);
}

// ---------------- mix + softmax (MFMA, [pos][h16] LDS + row permutation) ----
// LDS buffer: logical row r (k-pos) stored at PHYSICAL row r' = (r&3)*256 +
// (r>>2), each row ROWB=24 u16 (48 B stride, 16B-aligned). Row = h0..h11
// logits, zeros at 12..15, pad 16..23.
// Why the permutation (R4 post-mortem): thread t stages rows 4t..4t+3; with
// identity mapping the lane stride is 192 B == 16 dwords mod 32 -> 64 lanes
// hit 2 banks (32-way, 9.4M conflict cycles). With r', stage-in/out touch
// physical row i*256+t -> lane stride 48 B = 12 dwords -> start banks cycle
// {0,12,24,4,16,28,8,20}, b128 covers all 32 banks: minimum-cycle access.
// Fragment reads: (r&3)*256 rows * 48 B == 0 mod 128 B, so banking is
// unchanged (~4-way accepted); in-place uint2 writebacks ~3-way.
// Wave w still owns logical rows [256w,256w+256) end-to-end (same-wave
// in-place updates race-free; barriers unchanged).
#define ROWB 24

__global__ __launch_bounds__(256) void mix_softmax_kernel(
    const u16* __restrict__ attn, u16* __restrict__ attn2,
    const float* __restrict__ Wl, const float* __restrict__ bl,
    const float* __restrict__ Ww, const float* __restrict__ bw)
{
    __shared__ u16 buf[SS * ROWB];         // 48 KB
    __shared__ float wsum[4][16];
    __shared__ float invd[16];

    const int tid  = threadIdx.x;
    const int wave = tid >> 6;
    const int lane = tid & 63;
    const int u    = lane >> 4;            // 16-lane group within wave
    const int ln   = lane & 15;
    const int bL = blockIdx.x >> 10;
    const int qi = blockIdx.x & (SS - 1);
    const size_t gbase = ((size_t)bL * HH * SS + qi) * SS + tid * 4;

    // ---- stage-in: 12 uint2 loads, register transpose, vector LDS writes
    // logical rows 4*tid+i  ->  physical rows i*256+tid
    {
        uint2 src[HH];
#pragma unroll
        for (int h = 0; h < HH; ++h)
            src[h] = *(const uint2*)&attn[gbase + (size_t)h * SS * SS];

#pragma unroll
        for (int i = 0; i < 4; ++i) {
            const u32 sel = (i & 1) ? 0x07060302u : 0x05040100u;
            u32 w[6];
#pragma unroll
            for (int j = 0; j < 6; ++j) {
                const u32 lo = (i < 2) ? src[2 * j].x     : src[2 * j].y;
                const u32 hi = (i < 2) ? src[2 * j + 1].x : src[2 * j + 1].y;
                w[j] = __builtin_amdgcn_perm(hi, lo, sel);
            }
            uint4 q0; q0.x = w[0]; q0.y = w[1]; q0.z = w[2]; q0.w = w[3];
            uint4 q1; q1.x = w[4]; q1.y = w[5]; q1.z = 0u;   q1.w = 0u;
            *(uint4*)&buf[(i * 256 + tid) * ROWB + 0] = q0;
            *(uint4*)&buf[(i * 256 + tid) * ROWB + 8] = q1;
        }
    }

    // A1 frag: A[m=g][k=h] = Wl[h][g] * log2e, zero-padded
    bf16x8 a1;
    {
        u16 t[8];
#pragma unroll
        for (int j = 0; j < 8; ++j) {
            const int k = u * 8 + j;
            t[j] = (k < HH && ln < HH) ? f2bf(Wl[k * HH + ln] * 1.44269504f) : (u16)0;
        }
        __builtin_memcpy(&a1, t, 16);
    }
    f32x4 c1 = {0.f, 0.f, 0.f, 0.f};
#pragma unroll
    for (int r = 0; r < 4; ++r) {
        const int g = u * 4 + r;
        c1[r] = (g < HH) ? bl[g] * 1.44269504f : 0.f;
    }

    __syncthreads();

    const int posbase = wave * 256;
    const int fragoff = (u & 1) * 8;       // u>=2 read the finite (u&1) region
    // physical row for logical pos = posbase + mi*16 + ln:
    //   prow = (ln&3)*256 + (posbase + mi*16)/4 + (ln>>2)
    const int prow_ln = (ln & 3) * 256 + (ln >> 2);

    // ---- mix1 + exp; P-exp written back in place (same-wave rows)
    float part[4] = {0.f, 0.f, 0.f, 0.f};
#pragma unroll
    for (int mi = 0; mi < 16; ++mi) {
        const int prow = prow_ln + (posbase + mi * 16) / 4;
        const bf16x8 bfrag = *(const bf16x8*)&buf[prow * ROWB + fragoff];
        const f32x4 d = __builtin_amdgcn_mfma_f32_16x16x32_bf16(a1, bfrag, c1, 0, 0, 0);
        const float e0 = fast_exp2(d[0]);
        const float e1 = fast_exp2(d[1]);
        const float e2 = fast_exp2(d[2]);
        const float e3 = fast_exp2(d[3]);
        part[0] += e0; part[1] += e1; part[2] += e2; part[3] += e3;
        if (u < 3) {
            uint2 p;
            p.x = pack2(e0, e1); p.y = pack2(e2, e3);
            *(uint2*)&buf[prow * ROWB + u * 4] = p;
        }
    }

    // row-sum reduce: 16-lane butterfly, then cross-wave via tiny LDS array
#pragma unroll
    for (int off = 1; off < 16; off <<= 1) {
#pragma unroll
        for (int r = 0; r < 4; ++r) part[r] += __shfl_xor(part[r], off);
    }
    if (ln == 0) {
#pragma unroll
        for (int r = 0; r < 4; ++r) wsum[wave][u * 4 + r] = part[r];
    }
    __syncthreads();
    if (tid < 16)
        invd[tid] = 1.0f / (wsum[0][tid] + wsum[1][tid] + wsum[2][tid] + wsum[3][tid]);
    __syncthreads();

    // A2 frag: A[m=g2][k=g] = Ww[g][g2] * invden[g], zero-padded
    bf16x8 a2;
    {
        u16 t[8];
#pragma unroll
        for (int j = 0; j < 8; ++j) {
            const int k = u * 8 + j;
            t[j] = (k < HH && ln < HH) ? f2bf(Ww[k * HH + ln] * invd[k]) : (u16)0;
        }
        __builtin_memcpy(&a2, t, 16);
    }
    f32x4 c2 = {0.f, 0.f, 0.f, 0.f};
#pragma unroll
    for (int r = 0; r < 4; ++r) {
        const int g = u * 4 + r;
        c2[r] = (g < HH) ? bw[g] : 0.f;
    }

    // ---- mix2: read P rows, MFMA, write output in place
#pragma unroll
    for (int mi = 0; mi < 16; ++mi) {
        const int prow = prow_ln + (posbase + mi * 16) / 4;
        const bf16x8 bfrag = *(const bf16x8*)&buf[prow * ROWB + fragoff];
        const f32x4 d = __builtin_amdgcn_mfma_f32_16x16x32_bf16(a2, bfrag, c2, 0, 0, 0);
        if (u < 3) {
            uint2 p;
            p.x = pack2(d[0], d[1]); p.y = pack2(d[2], d[3]);
            *(uint2*)&buf[prow * ROWB + u * 4] = p;
        }
    }
    __syncthreads();

    // ---- stream-out: reverse register transpose -> 12 coalesced uint2 stores
    // logical rows 4*tid+i  <-  physical rows i*256+tid
    {
        u32 rw[4][6];
#pragma unroll
        for (int i = 0; i < 4; ++i) {
            const uint4 a = *(const uint4*)&buf[(i * 256 + tid) * ROWB + 0];
            const uint2 b = *(const uint2*)&buf[(i * 256 + tid) * ROWB + 8];
            rw[i][0] = a.x; rw[i][1] = a.y; rw[i][2] = a.z;
            rw[i][3] = a.w; rw[i][4] = b.x; rw[i][5] = b.y;
        }
#pragma unroll
        for (int g = 0; g < HH; ++g) {
            const u32 sel = (g & 1) ? 0x07060302u : 0x05040100u;
            uint2 p;
            p.x = __builtin_amdgcn_perm(rw[1][g >> 1], rw[0][g >> 1], sel);
            p.y = __builtin_amdgcn_perm(rw[3][g >> 1], rw[2][g >> 1], sel);
            *(uint2*)&attn2[gbase + (size_t)g * SS * SS] = p;
        }
    }
}

// ---------------- conversion kernels ----------------

__global__ __launch_bounds__(256) void cvt_bf16_kernel(
    const float* __restrict__ in, u16* __restrict__ out, int n8)
{
    const int i = blockIdx.x * 256 + threadIdx.x;
    if (i >= n8) return;
    const float4 a = ((const float4*)in)[i * 2];
    const float4 b = ((const float4*)in)[i * 2 + 1];
    uint4 p;
    p.x = pack2(a.x, a.y); p.y = pack2(a.z, a.w);
    p.z = pack2(b.x, b.y); p.w = pack2(b.z, b.w);
    ((uint4*)out)[i] = p;
}

__global__ __launch_bounds__(256) void cvt_transpose_kernel(
    const float* __restrict__ in, u16* __restrict__ out, int R, int C)
{
    __shared__ float t[32][33];
    const int c0 = blockIdx.x * 32, r0 = blockIdx.y * 32;
    const int tr = threadIdx.x >> 3;
    const int tc = (threadIdx.x & 7) * 4;
    const float4 v = *(const float4*)&in[(size_t)(r0 + tr) * C + c0 + tc];
    t[tc + 0][tr] = v.x; t[tc + 1][tr] = v.y;
    t[tc + 2][tr] = v.z; t[tc + 3][tr] = v.w;
    __syncthreads();
    uint2 p;
    p.x = pack2(t[tr][tc + 0], t[tr][tc + 1]);
    p.y = pack2(t[tr][tc + 2], t[tr][tc + 3]);
    *(uint2*)&out[(size_t)(c0 + tr) * R + r0 + tc] = p;
}

// ---------------- launch ----------------
extern "C" void kernel_launch(void* const* d_in, const int* in_sizes, int n_in,
                              void* d_out, int out_size, void* d_ws, size_t ws_size,
                              hipStream_t stream)
{
    const float* x     = (const float*)d_in[0];
    const float* Wqkv  = (const float*)d_in[1];
    const float* bqkv  = (const float*)d_in[2];
    const float* Wl    = (const float*)d_in[3];
    const float* bl    = (const float*)d_in[4];
    const float* Ww    = (const float*)d_in[5];
    const float* bw    = (const float*)d_in[6];
    const float* Wproj = (const float*)d_in[7];
    const float* bproj = (const float*)d_in[8];
    float* out = (float*)d_out;

    // workspace (bf16 elems)
    const size_t N_XB  = (size_t)BB * SS * DD;
    const size_t N_QB  = (size_t)BB * HH * SS * DH;
    const size_t N_WT  = (size_t)DD * 3 * DD;
    const size_t N_WP  = (size_t)DD * DD;
    const size_t N_AT1 = (size_t)HH * SS * SS;

    u16* xb  = (u16*)d_ws;
    u16* qb  = xb  + N_XB;
    u16* kb  = qb  + N_QB;
    u16* vb  = kb  + N_QB;
    u16* vt  = vb  + N_QB;
    u16* ctx = vt  + N_QB;
    u16* Wqkv_t = ctx + N_XB;
    u16* Wproj_t = Wqkv_t + N_WT;
    u16* attn = Wproj_t + N_WP;

    const size_t fixed_bytes = (size_t)(N_XB * 2 + N_QB * 4 + N_WT + N_WP) * 2;
    int b_per = BB;
    while (b_per > 1 &&
           fixed_bytes + (size_t)b_per * N_AT1 * 2 * 2 > ws_size)
        b_per >>= 1;
    const int n_iter = BB / b_per;
    u16* attn2 = attn + (size_t)b_per * N_AT1;

    const dim3 blk(256);

    // 0) conversions
    cvt_bf16_kernel<<<dim3((N_XB / 8 + 255) / 256), blk, 0, stream>>>(x, xb, (int)(N_XB / 8));
    cvt_transpose_kernel<<<dim3(3 * DD / 32, DD / 32), blk, 0, stream>>>(Wqkv, Wqkv_t, DD, 3 * DD);
    cvt_transpose_kernel<<<dim3(DD / 32, DD / 32), blk, 0, stream>>>(Wproj, Wproj_t, DD, DD);

    // 1) QKV projection (qb scaled, kb, vb) + v transpose
    qkv_gemm_kernel<<<dim3(3 * DD / 128, BB * SS / 128), blk, 0, stream>>>(
        xb, Wqkv_t, bqkv, qb, kb, vb);
    vtrans_kernel<<<dim3(SS / 64, BB * HH), blk, 0, stream>>>(vb, vt);

    for (int it = 0; it < n_iter; ++it) {
        const int bh0 = it * b_per * HH;
        // 2) logits
        qk_gemm_kernel<<<dim3(SS / 128, SS / 128, b_per * HH), blk, 0, stream>>>(
            qb, kb, attn, bh0);
        // 3) mix1 + softmax + mix2 (MFMA, permuted [pos][h] layout)
        mix_softmax_kernel<<<dim3(b_per * SS), blk, 0, stream>>>(
            attn, attn2, Wl, bl, Ww, bw);
        // 4) PV (64x64 tiles)
        pv_gemm_kernel<<<dim3(1, SS / 64, b_per * HH), blk, 0, stream>>>(
            attn2, vt, ctx, bh0);
    }

    // 5) output projection
    proj_gemm_kernel<<<dim3(DD / 64, BB * SS / 128), blk, 0, stream>>>(
        ctx, Wproj_t, bproj, out);
}

// Round 6
// 240.943 us; speedup vs baseline: 1.0497x; 1.0497x over previous
//
#include <hip/hip_runtime.h>
#include <cstdint>

// Problem constants: B=4, S=1024, D=768, H=12, dh=64
#define BB 4
#define SS 1024
#define DD 768
#define HH 12
#define DH 64

typedef unsigned short u16;
typedef unsigned int   u32;
typedef __attribute__((ext_vector_type(8))) short bf16x8;
typedef __attribute__((ext_vector_type(4))) float f32x4;

// fp32 -> bf16 RNE (finite values)
__device__ __forceinline__ u16 f2bf(float f) {
    u32 u = __float_as_uint(f);
    u += 0x7fffu + ((u >> 16) & 1u);
    return (u16)(u >> 16);
}
__device__ __forceinline__ float b2f(u32 lo16) {
    return __uint_as_float(lo16 << 16);
}

// 2^x via v_exp_f32 (gfx950 exp is base-2)
__device__ __forceinline__ float fast_exp2(float x) {
    return __builtin_amdgcn_exp2f(x);
}

// pack two f32 -> packed bf16x2. gfx950 has V_CVT_PK_BF16_F32.
#if __has_builtin(__builtin_amdgcn_cvt_pk_bf16_f32)
__device__ __forceinline__ u32 pack2(float a, float b) {
    auto r = __builtin_amdgcn_cvt_pk_bf16_f32(a, b);
    u32 v; __builtin_memcpy(&v, &r, 4); return v;
}
#else
__device__ __forceinline__ u32 pack2(float a, float b) {
    return (u32)f2bf(a) | ((u32)f2bf(b) << 16);
}
#endif

// async global->LDS, 16 B per lane. GLOBAL pointer is PER-LANE; LDS dest is
// wave-uniform base, HW adds lane*16 (m104/m108).
#define ASYNC16(gp, lp) __builtin_amdgcn_global_load_lds( \
    (const __attribute__((address_space(1))) void*)(gp),  \
    (__attribute__((address_space(3))) void*)(lp), 16, 0, 0)

// ---------------- MFMA GEMM body (NT: A[M,K], B[N,K], both K-contiguous bf16) ----
template<int BM_, int BN_, class Epi>
__device__ __forceinline__ void mfma_gemm(
    const u16* __restrict__ A, const u16* __restrict__ B,
    int K, int lda, int ldb, int m0, int n0, const Epi& epi)
{
    constexpr int MI = BM_ / 32;
    constexpr int NJ = BN_ / 32;
    __shared__ u16 Alds[BM_ * 32];
    __shared__ u16 Blds[BN_ * 32];

    const int tid  = threadIdx.x;
    const int wave = tid >> 6;
    const int lane = tid & 63;
    const int wr = wave >> 1, wc = wave & 1;

    const int ar = lane >> 2;
    const int ac = (lane & 3) * 8;

    f32x4 acc[MI][NJ] = {};

    for (int k0 = 0; k0 < K; k0 += 32) {
        __syncthreads();
#pragma unroll
        for (int j = 0; j < BM_ / 64; ++j) {
            const int rb = wave * (BM_ / 4) + j * 16;
            ASYNC16(A + (size_t)(m0 + rb + ar) * lda + k0 + ac, &Alds[rb * 32]);
        }
#pragma unroll
        for (int j = 0; j < BN_ / 64; ++j) {
            const int rb = wave * (BN_ / 4) + j * 16;
            ASYNC16(B + (size_t)(n0 + rb + ar) * ldb + k0 + ac, &Blds[rb * 32]);
        }
        __syncthreads();

        bf16x8 af[MI], bfr[NJ];
#pragma unroll
        for (int mi = 0; mi < MI; ++mi)
            af[mi] = *(const bf16x8*)&Alds[(wr * (BM_ / 2) + mi * 16 + (lane & 15)) * 32 + (lane >> 4) * 8];
#pragma unroll
        for (int nj = 0; nj < NJ; ++nj)
            bfr[nj] = *(const bf16x8*)&Blds[(wc * (BN_ / 2) + nj * 16 + (lane & 15)) * 32 + (lane >> 4) * 8];
#pragma unroll
        for (int mi = 0; mi < MI; ++mi)
#pragma unroll
            for (int nj = 0; nj < NJ; ++nj)
                acc[mi][nj] = __builtin_amdgcn_mfma_f32_16x16x32_bf16(
                    af[mi], bfr[nj], acc[mi][nj], 0, 0, 0);
    }

#pragma unroll
    for (int mi = 0; mi < MI; ++mi)
#pragma unroll
        for (int nj = 0; nj < NJ; ++nj)
#pragma unroll
            for (int r = 0; r < 4; ++r)
                epi(m0 + wr * (BM_ / 2) + mi * 16 + (lane >> 4) * 4 + r,
                    n0 + wc * (BN_ / 2) + nj * 16 + (lane & 15),
                    acc[mi][nj][r]);
}

// padded Clds row length (u16)
#define CPAD 136

// ---------------- qkv GEMM (custom, LDS-coalesced epilogue) ----------------
__global__ __launch_bounds__(256) void qkv_gemm_kernel(
    const u16* __restrict__ xb, const u16* __restrict__ Wt,
    const float* __restrict__ bias,
    u16* __restrict__ qb, u16* __restrict__ kb, u16* __restrict__ vb)
{
    __shared__ u16 Alds[128 * 32];
    __shared__ u16 Blds[128 * 32];
    __shared__ u16 Clds[128 * CPAD];

    const int tid  = threadIdx.x;
    const int wave = tid >> 6;
    const int lane = tid & 63;
    const int wr = wave >> 1, wc = wave & 1;
    const int ar = lane >> 2;
    const int ac = (lane & 3) * 8;
    const int m0 = blockIdx.y * 128, n0 = blockIdx.x * 128;

    f32x4 acc[4][4] = {};

    for (int k0 = 0; k0 < DD; k0 += 32) {
        __syncthreads();
#pragma unroll
        for (int j = 0; j < 2; ++j) {
            const int rb = wave * 32 + j * 16;
            ASYNC16(xb + (size_t)(m0 + rb + ar) * DD + k0 + ac, &Alds[rb * 32]);
            ASYNC16(Wt + (size_t)(n0 + rb + ar) * DD + k0 + ac, &Blds[rb * 32]);
        }
        __syncthreads();

        bf16x8 af[4], bfr[4];
#pragma unroll
        for (int mi = 0; mi < 4; ++mi)
            af[mi] = *(const bf16x8*)&Alds[(wr * 64 + mi * 16 + (lane & 15)) * 32 + (lane >> 4) * 8];
#pragma unroll
        for (int nj = 0; nj < 4; ++nj)
            bfr[nj] = *(const bf16x8*)&Blds[(wc * 64 + nj * 16 + (lane & 15)) * 32 + (lane >> 4) * 8];
#pragma unroll
        for (int mi = 0; mi < 4; ++mi)
#pragma unroll
            for (int nj = 0; nj < 4; ++nj)
                acc[mi][nj] = __builtin_amdgcn_mfma_f32_16x16x32_bf16(
                    af[mi], bfr[nj], acc[mi][nj], 0, 0, 0);
    }

    const int c  = n0 / DD;
    const int w0 = n0 - c * DD;
    const int hA = w0 >> 6;
    const float qs = (c == 0) ? 0.125f : 1.0f;
#pragma unroll
    for (int mi = 0; mi < 4; ++mi)
#pragma unroll
        for (int nj = 0; nj < 4; ++nj)
#pragma unroll
            for (int r = 0; r < 4; ++r) {
                const int row = wr * 64 + mi * 16 + (lane >> 4) * 4 + r;
                const int col = wc * 64 + nj * 16 + (lane & 15);
                Clds[row * CPAD + col] = f2bf((acc[mi][nj][r] + bias[n0 + col]) * qs);
            }
    __syncthreads();

    u16* const dst = (c == 0) ? qb : (c == 1) ? kb : vb;
    const int b = m0 >> 10;
#pragma unroll
    for (int j = 0; j < 8; ++j) {
        const int idx = j * 256 + tid;
        const int row = idx >> 4, u4 = idx & 15;
        const int half = u4 >> 3, d8 = u4 & 7;
        const int h = hA + half;
        const int s = (m0 + row) & 1023;
        const uint4 v = *(const uint4*)&Clds[row * CPAD + half * 64 + d8 * 8];
        *(uint4*)&dst[(((size_t)(b * HH + h) << 10) + s) * DH + d8 * 8] = v;
    }
}

// ---------------- vb -> vt transpose (per bh: 1024x64 -> 64x1024) ----------
__global__ __launch_bounds__(256) void vtrans_kernel(
    const u16* __restrict__ vb, u16* __restrict__ vt)
{
    __shared__ u16 t[64 * 72];
    const int tid = threadIdx.x;
    const int bh = blockIdx.y;
    const int s0 = blockIdx.x * 64;
    const u16* src = vb + ((size_t)bh << 16) + (size_t)s0 * DH;

#pragma unroll
    for (int j = 0; j < 2; ++j) {
        const int idx = j * 256 + tid;
        const int row = idx >> 3, u4 = idx & 7;
        *(uint4*)&t[row * 72 + u4 * 8] = *(const uint4*)&src[row * DH + u4 * 8];
    }
    __syncthreads();

#pragma unroll
    for (int j = 0; j < 2; ++j) {
        const int idx = j * 256 + tid;
        const int d = idx >> 3, u4 = idx & 7;
        u16 tmp[8];
#pragma unroll
        for (int i = 0; i < 8; ++i) tmp[i] = t[(u4 * 8 + i) * 72 + d];
        *(uint4*)&vt[((size_t)bh * DH + d) * SS + s0 + u4 * 8] = *(const uint4*)tmp;
    }
}

// ---------------- qk GEMM (custom, LDS-coalesced epilogue) -----------------
__global__ __launch_bounds__(256) void qk_gemm_kernel(
    const u16* __restrict__ qb, const u16* __restrict__ kb,
    u16* __restrict__ attn, int bh0)
{
    __shared__ u16 Alds[128 * 32];
    __shared__ u16 Blds[128 * 32];
    __shared__ u16 Clds[128 * CPAD];

    const int tid  = threadIdx.x;
    const int wave = tid >> 6;
    const int lane = tid & 63;
    const int wr = wave >> 1, wc = wave & 1;
    const int ar = lane >> 2;
    const int ac = (lane & 3) * 8;
    const int m0 = blockIdx.y * 128, n0 = blockIdx.x * 128;

    const int bhL = blockIdx.z;
    const u16* A = qb + (size_t)(bh0 + bhL) * SS * DH;
    const u16* B = kb + (size_t)(bh0 + bhL) * SS * DH;
    u16* C = attn + (size_t)bhL * SS * SS;

    f32x4 acc[4][4] = {};

#pragma unroll
    for (int k0 = 0; k0 < DH; k0 += 32) {
        __syncthreads();
#pragma unroll
        for (int j = 0; j < 2; ++j) {
            const int rb = wave * 32 + j * 16;
            ASYNC16(A + (size_t)(m0 + rb + ar) * DH + k0 + ac, &Alds[rb * 32]);
            ASYNC16(B + (size_t)(n0 + rb + ar) * DH + k0 + ac, &Blds[rb * 32]);
        }
        __syncthreads();

        bf16x8 af[4], bfr[4];
#pragma unroll
        for (int mi = 0; mi < 4; ++mi)
            af[mi] = *(const bf16x8*)&Alds[(wr * 64 + mi * 16 + (lane & 15)) * 32 + (lane >> 4) * 8];
#pragma unroll
        for (int nj = 0; nj < 4; ++nj)
            bfr[nj] = *(const bf16x8*)&Blds[(wc * 64 + nj * 16 + (lane & 15)) * 32 + (lane >> 4) * 8];
#pragma unroll
        for (int mi = 0; mi < 4; ++mi)
#pragma unroll
            for (int nj = 0; nj < 4; ++nj)
                acc[mi][nj] = __builtin_amdgcn_mfma_f32_16x16x32_bf16(
                    af[mi], bfr[nj], acc[mi][nj], 0, 0, 0);
    }

#pragma unroll
    for (int mi = 0; mi < 4; ++mi)
#pragma unroll
        for (int nj = 0; nj < 4; ++nj)
#pragma unroll
            for (int r = 0; r < 4; ++r) {
                const int row = wr * 64 + mi * 16 + (lane >> 4) * 4 + r;
                const int col = wc * 64 + nj * 16 + (lane & 15);
                Clds[row * CPAD + col] = f2bf(acc[mi][nj][r]);
            }
    __syncthreads();

#pragma unroll
    for (int j = 0; j < 8; ++j) {
        const int idx = j * 256 + tid;
        const int row = idx >> 4, u4 = idx & 15;
        *(uint4*)&C[(size_t)(m0 + row) * SS + n0 + u4 * 8] =
            *(const uint4*)&Clds[row * CPAD + u4 * 8];
    }
}

// ---------------- pv (64x64 tile) ------------------------------------------
__global__ __launch_bounds__(256) void pv_gemm_kernel(
    const u16* __restrict__ attn2, const u16* __restrict__ vt,
    u16* __restrict__ ctx, int bh0)
{
    const int bhL = blockIdx.z;
    const int bh = bh0 + bhL;
    const int b = bh / HH, h = bh % HH;
    const u16* A = attn2 + (size_t)bhL * SS * SS;
    const u16* B = vt + (size_t)bh * DH * SS;
    u16* C = ctx + (size_t)b * SS * DD + h * DH;
    struct Epi {
        u16* C;
        __device__ void operator()(int m, int n, float v) const {
            C[(size_t)m * DD + n] = f2bf(v);
        }
    } epi{C};
    mfma_gemm<64, 64>(A, B, SS, SS, SS, blockIdx.y * 64, 0, epi);
}

// ---------------- proj (template) ------------------------------------------
__global__ __launch_bounds__(256) void proj_gemm_kernel(
    const u16* __restrict__ ctx, const u16* __restrict__ Wt,
    const float* __restrict__ bias, float* __restrict__ out)
{
    struct Epi {
        float* out; const float* bias;
        __device__ void operator()(int m, int n, float v) const {
            out[(size_t)m * DD + n] = v + bias[n];
        }
    } epi{out, bias};
    mfma_gemm<128, 64>(ctx, Wt, DD, DD, DD, blockIdx.y * 128, blockIdx.x * 64, epi);
}

// ---------------- mix + softmax (MFMA, compact [pos][h16] swizzled LDS) -----
// Logical row r (k-pos) = 16 u16 (32 B): h0..h11 + zeros at 12..15.
// Physical layout (derived from the 16-lane-phase bank model that explains
// R4=9.4M / R5=11.3M conflicts):
//   * permuted rows: block = r&3, inner = r>>2 (stage-in lane-stride 32 B)
//   * XOR-half: physical 16B-unit = half ^ (inner&1)   (spreads stage banks)
//   * +16 B pad per block (block stride 8208 B = +4 dword banks per ln&3)
//     -> fragment reads/writebacks: 16 distinct start banks per 16-lane
//        phase = 2/bank = minimal; stage-in ~4-way on 16 ops (accepted).
// LDS 32.8 KB -> 4 blocks/CU (was 48 KB / 3 blocks, 28% occupancy).
#define BLKU 4104   // u16 per 256-row block (8208 B)

__device__ __forceinline__ int physIdx(int r, int half) {
    // u16 index of the 16B-unit `half` of logical row r
    return (r & 3) * BLKU + (r >> 2) * 16 + ((half ^ ((r >> 2) & 1)) << 3);
}

__global__ __launch_bounds__(256) void mix_softmax_kernel(
    const u16* __restrict__ attn, u16* __restrict__ attn2,
    const float* __restrict__ Wl, const float* __restrict__ bl,
    const float* __restrict__ Ww, const float* __restrict__ bw)
{
    __shared__ u16 buf[4 * BLKU];          // 32.8 KB
    __shared__ float wsum[4][16];
    __shared__ float invd[16];

    const int tid  = threadIdx.x;
    const int wave = tid >> 6;
    const int lane = tid & 63;
    const int u    = lane >> 4;            // 16-lane group within wave
    const int ln   = lane & 15;
    const int bL = blockIdx.x >> 10;
    const int qi = blockIdx.x & (SS - 1);
    const size_t gbase = ((size_t)bL * HH * SS + qi) * SS + tid * 4;

    // ---- stage-in: 12 uint2 loads, register transpose, vector LDS writes
    // logical rows 4*tid+i ; physical: block i, inner tid, XOR-half by tid&1
    {
        uint2 src[HH];
#pragma unroll
        for (int h = 0; h < HH; ++h)
            src[h] = *(const uint2*)&attn[gbase + (size_t)h * SS * SS];

#pragma unroll
        for (int i = 0; i < 4; ++i) {
            const u32 sel = (i & 1) ? 0x07060302u : 0x05040100u;
            u32 w[6];
#pragma unroll
            for (int j = 0; j < 6; ++j) {
                const u32 lo = (i < 2) ? src[2 * j].x     : src[2 * j].y;
                const u32 hi = (i < 2) ? src[2 * j + 1].x : src[2 * j + 1].y;
                w[j] = __builtin_amdgcn_perm(hi, lo, sel);
            }
            uint4 q0; q0.x = w[0]; q0.y = w[1]; q0.z = w[2]; q0.w = w[3];
            uint4 q1; q1.x = w[4]; q1.y = w[5]; q1.z = 0u;   q1.w = 0u;
            const int r = 4 * tid + i;
            *(uint4*)&buf[physIdx(r, 0)] = q0;
            *(uint4*)&buf[physIdx(r, 1)] = q1;
        }
    }

    // A1 frag: A[m=g][k=h] = Wl[h][g] * log2e, zero-padded
    bf16x8 a1;
    {
        u16 t[8];
#pragma unroll
        for (int j = 0; j < 8; ++j) {
            const int k = u * 8 + j;
            t[j] = (k < HH && ln < HH) ? f2bf(Wl[k * HH + ln] * 1.44269504f) : (u16)0;
        }
        __builtin_memcpy(&a1, t, 16);
    }
    f32x4 c1 = {0.f, 0.f, 0.f, 0.f};
#pragma unroll
    for (int r = 0; r < 4; ++r) {
        const int g = u * 4 + r;
        c1[r] = (g < HH) ? bl[g] * 1.44269504f : 0.f;
    }

    __syncthreads();

    const int posbase = wave * 256;
    const int uh = u & 1;                  // u>=2 read the finite (u&1) unit

    // ---- mix1 + exp; P-exp written back in place (same-wave rows)
    float part[4] = {0.f, 0.f, 0.f, 0.f};
#pragma unroll
    for (int mi = 0; mi < 16; ++mi) {
        const int r = posbase + mi * 16 + ln;
        const bf16x8 bfrag = *(const bf16x8*)&buf[physIdx(r, uh)];
        const f32x4 d = __builtin_amdgcn_mfma_f32_16x16x32_bf16(a1, bfrag, c1, 0, 0, 0);
        const float e0 = fast_exp2(d[0]);
        const float e1 = fast_exp2(d[1]);
        const float e2 = fast_exp2(d[2]);
        const float e3 = fast_exp2(d[3]);
        part[0] += e0; part[1] += e1; part[2] += e2; part[3] += e3;
        if (u < 3) {
            uint2 p;
            p.x = pack2(e0, e1); p.y = pack2(e2, e3);
            *(uint2*)&buf[physIdx(r, u >> 1) + (u & 1) * 4] = p;
        }
    }

    // row-sum reduce: 16-lane butterfly, then cross-wave via tiny LDS array
#pragma unroll
    for (int off = 1; off < 16; off <<= 1) {
#pragma unroll
        for (int r = 0; r < 4; ++r) part[r] += __shfl_xor(part[r], off);
    }
    if (ln == 0) {
#pragma unroll
        for (int r = 0; r < 4; ++r) wsum[wave][u * 4 + r] = part[r];
    }
    __syncthreads();
    if (tid < 16)
        invd[tid] = 1.0f / (wsum[0][tid] + wsum[1][tid] + wsum[2][tid] + wsum[3][tid]);
    __syncthreads();

    // A2 frag: A[m=g2][k=g] = Ww[g][g2] * invden[g], zero-padded
    bf16x8 a2;
    {
        u16 t[8];
#pragma unroll
        for (int j = 0; j < 8; ++j) {
            const int k = u * 8 + j;
            t[j] = (k < HH && ln < HH) ? f2bf(Ww[k * HH + ln] * invd[k]) : (u16)0;
        }
        __builtin_memcpy(&a2, t, 16);
    }
    f32x4 c2 = {0.f, 0.f, 0.f, 0.f};
#pragma unroll
    for (int r = 0; r < 4; ++r) {
        const int g = u * 4 + r;
        c2[r] = (g < HH) ? bw[g] : 0.f;
    }

    // ---- mix2: read P rows, MFMA, write output in place
#pragma unroll
    for (int mi = 0; mi < 16; ++mi) {
        const int r = posbase + mi * 16 + ln;
        const bf16x8 bfrag = *(const bf16x8*)&buf[physIdx(r, uh)];
        const f32x4 d = __builtin_amdgcn_mfma_f32_16x16x32_bf16(a2, bfrag, c2, 0, 0, 0);
        if (u < 3) {
            uint2 p;
            p.x = pack2(d[0], d[1]); p.y = pack2(d[2], d[3]);
            *(uint2*)&buf[physIdx(r, u >> 1) + (u & 1) * 4] = p;
        }
    }
    __syncthreads();

    // ---- stream-out: reverse register transpose -> 12 coalesced uint2 stores
    {
        u32 rw[4][6];
#pragma unroll
        for (int i = 0; i < 4; ++i) {
            const int r = 4 * tid + i;
            const uint4 a = *(const uint4*)&buf[physIdx(r, 0)];
            const uint2 b = *(const uint2*)&buf[physIdx(r, 1)];
            rw[i][0] = a.x; rw[i][1] = a.y; rw[i][2] = a.z;
            rw[i][3] = a.w; rw[i][4] = b.x; rw[i][5] = b.y;
        }
#pragma unroll
        for (int g = 0; g < HH; ++g) {
            const u32 sel = (g & 1) ? 0x07060302u : 0x05040100u;
            uint2 p;
            p.x = __builtin_amdgcn_perm(rw[1][g >> 1], rw[0][g >> 1], sel);
            p.y = __builtin_amdgcn_perm(rw[3][g >> 1], rw[2][g >> 1], sel);
            *(uint2*)&attn2[gbase + (size_t)g * SS * SS] = p;
        }
    }
}

// ---------------- conversion kernels ----------------

__global__ __launch_bounds__(256) void cvt_bf16_kernel(
    const float* __restrict__ in, u16* __restrict__ out, int n8)
{
    const int i = blockIdx.x * 256 + threadIdx.x;
    if (i >= n8) return;
    const float4 a = ((const float4*)in)[i * 2];
    const float4 b = ((const float4*)in)[i * 2 + 1];
    uint4 p;
    p.x = pack2(a.x, a.y); p.y = pack2(a.z, a.w);
    p.z = pack2(b.x, b.y); p.w = pack2(b.z, b.w);
    ((uint4*)out)[i] = p;
}

__global__ __launch_bounds__(256) void cvt_transpose_kernel(
    const float* __restrict__ in, u16* __restrict__ out, int R, int C)
{
    __shared__ float t[32][33];
    const int c0 = blockIdx.x * 32, r0 = blockIdx.y * 32;
    const int tr = threadIdx.x >> 3;
    const int tc = (threadIdx.x & 7) * 4;
    const float4 v = *(const float4*)&in[(size_t)(r0 + tr) * C + c0 + tc];
    t[tc + 0][tr] = v.x; t[tc + 1][tr] = v.y;
    t[tc + 2][tr] = v.z; t[tc + 3][tr] = v.w;
    __syncthreads();
    uint2 p;
    p.x = pack2(t[tr][tc + 0], t[tr][tc + 1]);
    p.y = pack2(t[tr][tc + 2], t[tr][tc + 3]);
    *(uint2*)&out[(size_t)(c0 + tr) * R + r0 + tc] = p;
}

// ---------------- launch ----------------
extern "C" void kernel_launch(void* const* d_in, const int* in_sizes, int n_in,
                              void* d_out, int out_size, void* d_ws, size_t ws_size,
                              hipStream_t stream)
{
    const float* x     = (const float*)d_in[0];
    const float* Wqkv  = (const float*)d_in[1];
    const float* bqkv  = (const float*)d_in[2];
    const float* Wl    = (const float*)d_in[3];
    const float* bl    = (const float*)d_in[4];
    const float* Ww    = (const float*)d_in[5];
    const float* bw    = (const float*)d_in[6];
    const float* Wproj = (const float*)d_in[7];
    const float* bproj = (const float*)d_in[8];
    float* out = (float*)d_out;

    // workspace (bf16 elems)
    const size_t N_XB  = (size_t)BB * SS * DD;
    const size_t N_QB  = (size_t)BB * HH * SS * DH;
    const size_t N_WT  = (size_t)DD * 3 * DD;
    const size_t N_WP  = (size_t)DD * DD;
    const size_t N_AT1 = (size_t)HH * SS * SS;

    u16* xb  = (u16*)d_ws;
    u16* qb  = xb  + N_XB;
    u16* kb  = qb  + N_QB;
    u16* vb  = kb  + N_QB;
    u16* vt  = vb  + N_QB;
    u16* ctx = vt  + N_QB;
    u16* Wqkv_t = ctx + N_XB;
    u16* Wproj_t = Wqkv_t + N_WT;
    u16* attn = Wproj_t + N_WP;

    const size_t fixed_bytes = (size_t)(N_XB * 2 + N_QB * 4 + N_WT + N_WP) * 2;
    int b_per = BB;
    while (b_per > 1 &&
           fixed_bytes + (size_t)b_per * N_AT1 * 2 * 2 > ws_size)
        b_per >>= 1;
    const int n_iter = BB / b_per;
    u16* attn2 = attn + (size_t)b_per * N_AT1;

    const dim3 blk(256);

    // 0) conversions
    cvt_bf16_kernel<<<dim3((N_XB / 8 + 255) / 256), blk, 0, stream>>>(x, xb, (int)(N_XB / 8));
    cvt_transpose_kernel<<<dim3(3 * DD / 32, DD / 32), blk, 0, stream>>>(Wqkv, Wqkv_t, DD, 3 * DD);
    cvt_transpose_kernel<<<dim3(DD / 32, DD / 32), blk, 0, stream>>>(Wproj, Wproj_t, DD, DD);

    // 1) QKV projection (qb scaled, kb, vb) + v transpose
    qkv_gemm_kernel<<<dim3(3 * DD / 128, BB * SS / 128), blk, 0, stream>>>(
        xb, Wqkv_t, bqkv, qb, kb, vb);
    vtrans_kernel<<<dim3(SS / 64, BB * HH), blk, 0, stream>>>(vb, vt);

    for (int it = 0; it < n_iter; ++it) {
        const int bh0 = it * b_per * HH;
        // 2) logits
        qk_gemm_kernel<<<dim3(SS / 128, SS / 128, b_per * HH), blk, 0, stream>>>(
            qb, kb, attn, bh0);
        // 3) mix1 + softmax + mix2 (MFMA, compact swizzled [pos][h] layout)
        mix_softmax_kernel<<<dim3(b_per * SS), blk, 0, stream>>>(
            attn, attn2, Wl, bl, Ww, bw);
        // 4) PV (64x64 tiles)
        pv_gemm_kernel<<<dim3(1, SS / 64, b_per * HH), blk, 0, stream>>>(
            attn2, vt, ctx, bh0);
    }

    // 5) output projection
    proj_gemm_kernel<<<dim3(DD / 64, BB * SS / 128), blk, 0, stream>>>(
        ctx, Wproj_t, bproj, out);
}